// Round 3
// baseline (151.779 us; speedup 1.0000x reference)
//
#include <hip/hip_runtime.h>
#include <math.h>

// Problem constants (from reference setup_inputs)
#define BB 16
#define CC 85
#define HH 128
#define WW 128
#define NGT 64
#define HW (HH * WW)          // 16384
#define NC (CC - 5)           // 80
#define NCH 81                // channels 4..84 (obj + 80 cls)
#define NPART (BB * NCH)      // 1296 partial sums

// ws layout: [0 .. NPART) floats : per-block partial softplus sums
//            (slot = b*81 + (c-4)); nothing else — no accumulators, no memset.

__device__ __forceinline__ float softplus_f(float x) {
    // logaddexp(x,0) = max(x,0) + log1p(exp(-|x|)); exp(-|x|) in (0,1] so no
    // cancellation; ~1e-7 rel error, and the final means divide by 16384 / 1.3M.
    float ax = fabsf(x);
    float e = __expf(-ax);
    return fmaxf(x, 0.0f) + __logf(1.0f + e);
}

// Dense softplus sum over channels 4..84. Grid: NPART blocks x 256 thr.
// Block bk covers channel slice (b = bk/81, c = 4 + bk%81): 16384 elems =
// 4096 float4 = 256 threads x 16 float4. One partial store per block.
__global__ __launch_bounds__(256) void bce_sum_kernel(const float* __restrict__ preds,
                                                      float* __restrict__ part) {
    const int bk = blockIdx.x;
    const int b = bk / NCH;
    const int c = 4 + (bk - b * NCH);
    const float4* p = (const float4*)(preds + ((size_t)(b * CC + c) * HW));

    float s = 0.0f;
    #pragma unroll
    for (int k = 0; k < 16; ++k) {
        float4 v = p[threadIdx.x + (k << 8)];
        s += softplus_f(v.x) + softplus_f(v.y) + softplus_f(v.z) + softplus_f(v.w);
    }

    #pragma unroll
    for (int off = 32; off > 0; off >>= 1) s += __shfl_down(s, off, 64);

    __shared__ float wsum[4];
    const int lane = threadIdx.x & 63;
    const int wv = threadIdx.x >> 6;
    if (lane == 0) wsum[wv] = s;
    __syncthreads();
    if (threadIdx.x == 0) part[bk] = wsum[0] + wsum[1] + wsum[2] + wsum[3];
}

// Fused tail: per-GT gather+IoU+dedup (one thread per GT, 16x64=1024) AND the
// final reduction of the 1296 dense partials. Single block, no atomics.
__global__ __launch_bounds__(1024) void tail_kernel(const float* __restrict__ preds,
                                                    const float* __restrict__ tgt,
                                                    const float* __restrict__ part,
                                                    float* __restrict__ out) {
    const int tid = threadIdx.x;          // 0..1023
    const int b = tid >> 6;               // batch
    const int n = tid & 63;               // GT index within batch

    const float* t = tgt + (size_t)tid * 5;
    const int cls = (int)t[0];
    const float cx = t[1], cy = t[2], w = t[3], h = t[4];
    const int gi = (int)(cx * (float)WW);
    const int gj = (int)(cy * (float)HH);
    const int idx = gj * WW + gi;

    const float* pb = preds + (size_t)b * CC * HW + idx;
    const float px   = pb[0 * HW];
    const float py   = pb[1 * HW];
    const float pw   = pb[2 * HW];
    const float ph   = pb[3 * HW];
    const float pobj = pb[4 * HW];
    const float pcls = pb[(5 + cls) * HW];

    // boxes exactly as the reference computes them
    const float p0 = px - pw * 0.5f, p1 = py - ph * 0.5f;
    const float p2 = px + pw * 0.5f, p3 = py + ph * 0.5f;
    const float g0 = (cx - w * 0.5f) * WW, g1 = (cy - h * 0.5f) * HH;
    const float g2 = (cx + w * 0.5f) * WW, g3 = (cy + h * 0.5f) * HH;

    const float ix1 = fmaxf(p0, g0), iy1 = fmaxf(p1, g1);
    const float ix2 = fminf(p2, g2), iy2 = fminf(p3, g3);
    const float inter = fmaxf(ix2 - ix1, 0.0f) * fmaxf(iy2 - iy1, 0.0f);
    const float a1 = (p2 - p0) * (p3 - p1);
    const float a2 = (g2 - g0) * (g3 - g1);
    const float iou = inter / (a1 + a2 - inter + 1e-7f);
    float box = 1.0f - iou;

    // set-semantics dedup within this batch: a cell counts once for obj,
    // a (cell,cls) pair once for cls.
    __shared__ int s_idx[BB * NGT];
    __shared__ int s_cls[BB * NGT];
    s_idx[tid] = idx;
    s_cls[tid] = cls;
    __syncthreads();
    bool dup_o = false, dup_c = false;
    const int base = b << 6;
    for (int m = base; m < base + n; ++m) {
        if (s_idx[m] == idx) {
            dup_o = true;
            if (s_cls[m] == cls) dup_c = true;
        }
    }
    float sub_o = dup_o ? 0.0f : pobj;   // gathered obj logits to subtract
    float sub_c = dup_c ? 0.0f : pcls;   // gathered cls logits to subtract

    // dense partial sums: 1296 slots over 1024 threads (slot tid and tid+1024)
    double obj_d = 0.0, cls_d = 0.0;
    {
        double v0 = (double)part[tid];
        if (tid % NCH == 0) obj_d += v0; else cls_d += v0;
        int k2 = tid + 1024;
        if (k2 < NPART) {
            double v1 = (double)part[k2];
            if (k2 % NCH == 0) obj_d += v1; else cls_d += v1;
        }
    }

    // wave64 reductions
    #pragma unroll
    for (int off = 32; off > 0; off >>= 1) {
        box   += __shfl_down(box,   off, 64);
        sub_o += __shfl_down(sub_o, off, 64);
        sub_c += __shfl_down(sub_c, off, 64);
        obj_d += __shfl_down(obj_d, off, 64);
        cls_d += __shfl_down(cls_d, off, 64);
    }

    __shared__ float  r_box[16], r_so[16], r_sc[16];
    __shared__ double r_od[16], r_cd[16];
    const int wv = tid >> 6;
    if ((tid & 63) == 0) {
        r_box[wv] = box; r_so[wv] = sub_o; r_sc[wv] = sub_c;
        r_od[wv] = obj_d; r_cd[wv] = cls_d;
    }
    __syncthreads();
    if (tid == 0) {
        float bx = 0.0f, so = 0.0f, sc = 0.0f;
        double od = 0.0, cd = 0.0;
        #pragma unroll
        for (int i = 0; i < 16; ++i) {
            bx += r_box[i]; so += r_so[i]; sc += r_sc[i];
            od += r_od[i];  cd += r_cd[i];
        }
        double obj = (od - (double)so) / (double)HW;
        double cls = (cd - (double)sc) / ((double)HW * (double)NC);
        out[0] = (float)(0.05 * (double)bx + 1.0 * obj + 0.5 * cls);
    }
}

extern "C" void kernel_launch(void* const* d_in, const int* in_sizes, int n_in,
                              void* d_out, int out_size, void* d_ws, size_t ws_size,
                              hipStream_t stream) {
    const float* preds = (const float*)d_in[0];
    const float* targets = (const float*)d_in[1];
    float* out = (float*)d_out;
    float* part = (float*)d_ws;

    bce_sum_kernel<<<NPART, 256, 0, stream>>>(preds, part);
    tail_kernel<<<1, 1024, 0, stream>>>(preds, targets, part, out);
}

// Round 4
// 133.608 us; speedup vs baseline: 1.1360x; 1.1360x over previous
//
#include <hip/hip_runtime.h>
#include <math.h>

// Problem constants (from reference setup_inputs)
#define BB 16
#define CC 85
#define HH 128
#define WW 128
#define NGT 64
#define HW (HH * WW)          // 16384
#define NC (CC - 5)           // 80
#define NCH 81                // channels 4..84 (obj + 80 cls)
#define NPART (BB * NCH)      // 1296 dense partial sums

// ws layout (floats):
//   [0 .. NPART)                : dense per-slice softplus sums (slot = b*81 + (c-4))
//   [NPART + 0*BB .. +1*BB)     : per-batch box-loss partials
//   [NPART + 1*BB .. +2*BB)     : per-batch gathered-obj partials (to subtract)
//   [NPART + 2*BB .. +3*BB)     : per-batch gathered-cls partials (to subtract)

__device__ __forceinline__ float softplus_f(float x) {
    // logaddexp(x,0) = max(x,0) + log1p(exp(-|x|)); exp(-|x|) in (0,1] so no
    // cancellation; ~1e-7 rel error, and the final means divide by 16384 / 1.3M.
    float ax = fabsf(x);
    float e = __expf(-ax);
    return fmaxf(x, 0.0f) + __logf(1.0f + e);
}

// Fused kernel. Grid: NPART + BB blocks x 256 threads.
//   blocks [0, NPART)      : dense softplus sum over one (b, c) channel slice
//   blocks [NPART, +BB)    : GT gather + IoU + set-dedup for one batch
// The 16 scatter-heavy GT blocks overlap the dense streaming blocks on other
// CUs, hiding their ~900-cycle per-round gather latency.
__global__ __launch_bounds__(256) void fused_kernel(const float* __restrict__ preds,
                                                    const float* __restrict__ tgt,
                                                    float* __restrict__ ws) {
    const int bk = blockIdx.x;
    if (bk < NPART) {
        // ---- dense path: 16384 elems = 256 threads x 16 float4 ----
        const int b = bk / NCH;
        const int c = 4 + (bk - b * NCH);
        const float4* p = (const float4*)(preds + ((size_t)(b * CC + c) * HW));

        float s = 0.0f;
        #pragma unroll
        for (int k = 0; k < 16; ++k) {
            float4 v = p[threadIdx.x + (k << 8)];
            s += softplus_f(v.x) + softplus_f(v.y) + softplus_f(v.z) + softplus_f(v.w);
        }

        #pragma unroll
        for (int off = 32; off > 0; off >>= 1) s += __shfl_down(s, off, 64);

        __shared__ float wsum[4];
        const int lane = threadIdx.x & 63;
        const int wv = threadIdx.x >> 6;
        if (lane == 0) wsum[wv] = s;
        __syncthreads();
        if (threadIdx.x == 0) ws[bk] = wsum[0] + wsum[1] + wsum[2] + wsum[3];
    } else {
        // ---- GT path: one batch, one GT per lane of wave 0 ----
        const int b = bk - NPART;
        const int n = threadIdx.x;
        __shared__ int s_idx[NGT];
        __shared__ int s_cls[NGT];

        float box = 0.0f, sub_o = 0.0f, sub_c = 0.0f;
        int idx = 0, cls = 0;
        float px = 0, py = 0, pw = 0, ph = 0, pobj = 0, pcls = 0;
        float cx = 0, cy = 0, w = 0, h = 0;

        if (n < NGT) {
            const float* t = tgt + ((size_t)(b * NGT + n)) * 5;
            cls = (int)t[0];
            cx = t[1]; cy = t[2]; w = t[3]; h = t[4];
            const int gi = (int)(cx * (float)WW);
            const int gj = (int)(cy * (float)HH);
            idx = gj * WW + gi;
            s_idx[n] = idx;
            s_cls[n] = cls;
            // issue scattered gathers early; latency overlaps the dedup barrier
            const float* pb = preds + (size_t)b * CC * HW + idx;
            px   = pb[0 * HW];
            py   = pb[1 * HW];
            pw   = pb[2 * HW];
            ph   = pb[3 * HW];
            pobj = pb[4 * HW];
            pcls = pb[(5 + cls) * HW];
        }
        __syncthreads();

        if (n < NGT) {
            // boxes exactly as the reference computes them
            const float p0 = px - pw * 0.5f, p1 = py - ph * 0.5f;
            const float p2 = px + pw * 0.5f, p3 = py + ph * 0.5f;
            const float g0 = (cx - w * 0.5f) * WW, g1 = (cy - h * 0.5f) * HH;
            const float g2 = (cx + w * 0.5f) * WW, g3 = (cy + h * 0.5f) * HH;

            const float ix1 = fmaxf(p0, g0), iy1 = fmaxf(p1, g1);
            const float ix2 = fminf(p2, g2), iy2 = fminf(p3, g3);
            const float inter = fmaxf(ix2 - ix1, 0.0f) * fmaxf(iy2 - iy1, 0.0f);
            const float a1 = (p2 - p0) * (p3 - p1);
            const float a2 = (g2 - g0) * (g3 - g1);
            const float iou = inter / (a1 + a2 - inter + 1e-7f);
            box = 1.0f - iou;

            // set semantics: a cell counts once (obj); a (cell,cls) pair once (cls)
            bool dup_o = false, dup_c = false;
            for (int m = 0; m < n; ++m) {
                if (s_idx[m] == idx) {
                    dup_o = true;
                    if (s_cls[m] == cls) dup_c = true;
                }
            }
            sub_o = dup_o ? 0.0f : pobj;
            sub_c = dup_c ? 0.0f : pcls;
        }

        if (n < 64) {   // wave 0 only
            #pragma unroll
            for (int off = 32; off > 0; off >>= 1) {
                box   += __shfl_down(box,   off, 64);
                sub_o += __shfl_down(sub_o, off, 64);
                sub_c += __shfl_down(sub_c, off, 64);
            }
            if (n == 0) {
                ws[NPART + 0 * BB + b] = box;
                ws[NPART + 1 * BB + b] = sub_o;
                ws[NPART + 2 * BB + b] = sub_c;
            }
        }
    }
}

// Final reduce: 1 block x 256 threads over 1296 dense partials + 48 GT partials.
__global__ __launch_bounds__(256) void reduce_kernel(const float* __restrict__ ws,
                                                     float* __restrict__ out) {
    const int tid = threadIdx.x;
    double obj = 0.0, cls = 0.0;
    for (int k = tid; k < NPART; k += 256) {
        double v = (double)ws[k];
        if (k % NCH == 0) obj += v; else cls += v;   // c==4 slots are obj
    }
    float box = 0.0f, sub_o = 0.0f, sub_c = 0.0f;
    if (tid < BB) {
        box   = ws[NPART + 0 * BB + tid];
        sub_o = ws[NPART + 1 * BB + tid];
        sub_c = ws[NPART + 2 * BB + tid];
    }

    __shared__ double so[256], sc[256];
    __shared__ float sb[256], sso[256], ssc[256];
    so[tid] = obj; sc[tid] = cls; sb[tid] = box; sso[tid] = sub_o; ssc[tid] = sub_c;
    __syncthreads();
    for (int s = 128; s > 0; s >>= 1) {
        if (tid < s) {
            so[tid] += so[tid + s];
            sc[tid] += sc[tid + s];
            sb[tid] += sb[tid + s];
            sso[tid] += sso[tid + s];
            ssc[tid] += ssc[tid + s];
        }
        __syncthreads();
    }
    if (tid == 0) {
        double o = (so[0] - (double)sso[0]) / (double)HW;
        double c = (sc[0] - (double)ssc[0]) / ((double)HW * (double)NC);
        out[0] = (float)(0.05 * (double)sb[0] + 1.0 * o + 0.5 * c);
    }
}

extern "C" void kernel_launch(void* const* d_in, const int* in_sizes, int n_in,
                              void* d_out, int out_size, void* d_ws, size_t ws_size,
                              hipStream_t stream) {
    const float* preds = (const float*)d_in[0];
    const float* targets = (const float*)d_in[1];
    float* out = (float*)d_out;
    float* ws = (float*)d_ws;

    fused_kernel<<<NPART + BB, 256, 0, stream>>>(preds, targets, ws);
    reduce_kernel<<<1, 256, 0, stream>>>(ws, out);
}